// Round 27
// baseline (270.439 us; speedup 1.0000x reference)
//
#include <hip/hip_runtime.h>
#include <hip/hip_bf16.h>

// Transformer block forward: B=2, T=2048, E=1024, H=16, D=64.
// Pipeline: prep (transposes+LN1) | QKV GEMM (128^2 swz, V written transposed
//           in epilogue, Q pre-scaled by 0.125*log2e) | flash attn v16
//           (no-max base-2 softmax, kv-tile PAIRS per iteration: amortized
//           lgkm drain + QK(b)||exp(a) overlap) | out-proj+res (64x128) |
//           LN2 | FC+GELU (128^2) | proj+res (64x128).

#define T_DIM 2048
#define E_DIM 1024
#define NH 16

using short8 = __attribute__((__ext_vector_type__(8))) short;
using f32x4  = __attribute__((__ext_vector_type__(4))) float;

static __device__ __forceinline__ f32x4 zero4() {
  f32x4 z = {0.f, 0.f, 0.f, 0.f};
  return z;
}

static __device__ __forceinline__ unsigned short f2bfbits(float f) {
  __hip_bfloat16 h = __float2bfloat16(f);
  return *reinterpret_cast<unsigned short*>(&h);
}

static __device__ __forceinline__ float gelu_tanh(float x) {
  float z = 0.7978845608028654f * (x + 0.044715f * x * x * x);
  float e = __expf(2.0f * z);
  float th = 1.0f - 2.0f / (e + 1.0f);
  return 0.5f * x * (1.0f + th);
}

// ---------------- prep: 4 weight transposes (f32 [K][N] -> bf16 [N][K]) + LN1 ----
__global__ __launch_bounds__(256) void prep(
    const float* __restrict__ w_qkv, const float* __restrict__ w_out,
    const float* __restrict__ w_fc, const float* __restrict__ w_proj,
    __hip_bfloat16* __restrict__ t_qkv, __hip_bfloat16* __restrict__ t_out,
    __hip_bfloat16* __restrict__ t_fc, __hip_bfloat16* __restrict__ t_proj,
    const float* __restrict__ x, const float* __restrict__ g,
    const float* __restrict__ bb, __hip_bfloat16* __restrict__ ln1o) {
  __shared__ float tl[64][65];
  const int id = blockIdx.x;
  const int t = threadIdx.x;
  if (id < 3072) {
    const float* in;
    __hip_bfloat16* out;
    int K, N, bx, by;
    if (id < 768) {
      in = w_qkv; out = t_qkv; K = 1024; N = 3072; bx = id % 48; by = id / 48;
    } else if (id < 1024) {
      const int i = id - 768;
      in = w_out; out = t_out; K = 1024; N = 1024; bx = i % 16; by = i / 16;
    } else if (id < 2048) {
      const int i = id - 1024;
      in = w_fc; out = t_fc; K = 1024; N = 4096; bx = i % 64; by = i / 64;
    } else {
      const int i = id - 2048;
      in = w_proj; out = t_proj; K = 4096; N = 1024; bx = i % 16; by = i / 16;
    }
    const int n0 = bx * 64, k0 = by * 64;
    const int rr = t >> 4;        // 0..15
    const int cc = (t & 15) * 4;  // 0..60
#pragma unroll
    for (int i = 0; i < 4; ++i) {
      const int row = rr + i * 16;
      const float4 v = *reinterpret_cast<const float4*>(&in[(size_t)(k0 + row) * N + n0 + cc]);
      tl[row][cc] = v.x; tl[row][cc + 1] = v.y; tl[row][cc + 2] = v.z; tl[row][cc + 3] = v.w;
    }
    __syncthreads();
#pragma unroll
    for (int i = 0; i < 4; ++i) {
      const int row = rr + i * 16;  // output row (n)
      ushort4 pk;
      pk.x = f2bfbits(tl[cc + 0][row]);
      pk.y = f2bfbits(tl[cc + 1][row]);
      pk.z = f2bfbits(tl[cc + 2][row]);
      pk.w = f2bfbits(tl[cc + 3][row]);
      *reinterpret_cast<ushort4*>(&out[(size_t)(n0 + row) * K + k0 + cc]) = pk;
    }
  } else {
    // LN1
    const int lane = t & 63;
    const int row = (id - 3072) * 4 + (t >> 6);
    const float* xr = x + (size_t)row * E_DIM;
    float4 v[4];
    float s = 0.f, s2 = 0.f;
#pragma unroll
    for (int i = 0; i < 4; ++i) {
      v[i] = *reinterpret_cast<const float4*>(&xr[(i * 64 + lane) * 4]);
      s  += v[i].x + v[i].y + v[i].z + v[i].w;
      s2 += v[i].x * v[i].x + v[i].y * v[i].y + v[i].z * v[i].z + v[i].w * v[i].w;
    }
#pragma unroll
    for (int m = 1; m < 64; m <<= 1) { s += __shfl_xor(s, m); s2 += __shfl_xor(s2, m); }
    const float mu = s * (1.0f / E_DIM);
    const float var = s2 * (1.0f / E_DIM) - mu * mu;
    const float rstd = rsqrtf(var + 1e-5f);
    __hip_bfloat16* orow = ln1o + (size_t)row * E_DIM;
#pragma unroll
    for (int i = 0; i < 4; ++i) {
      const int col = (i * 64 + lane) * 4;
      const float4 gv = *reinterpret_cast<const float4*>(&g[col]);
      const float4 bv = *reinterpret_cast<const float4*>(&bb[col]);
      ushort4 pk;
      pk.x = f2bfbits((v[i].x - mu) * rstd * gv.x + bv.x);
      pk.y = f2bfbits((v[i].y - mu) * rstd * gv.y + bv.y);
      pk.z = f2bfbits((v[i].z - mu) * rstd * gv.z + bv.z);
      pk.w = f2bfbits((v[i].w - mu) * rstd * gv.w + bv.w);
      *reinterpret_cast<ushort4*>(&orow[col]) = pk;
    }
  }
}

// ---------------- LayerNorm rows of 1024, f32 in -> bf16 out (LN2) ----------------
__global__ __launch_bounds__(256) void layernorm_bf16(
    const float* __restrict__ x, const float* __restrict__ g, const float* __restrict__ bb,
    __hip_bfloat16* __restrict__ out) {
  const int lane = threadIdx.x & 63;
  const int row = blockIdx.x * 4 + (threadIdx.x >> 6);
  const float* xr = x + (size_t)row * E_DIM;
  float4 v[4];
  float s = 0.f, s2 = 0.f;
#pragma unroll
  for (int i = 0; i < 4; ++i) {
    v[i] = *reinterpret_cast<const float4*>(&xr[(i * 64 + lane) * 4]);
    s  += v[i].x + v[i].y + v[i].z + v[i].w;
    s2 += v[i].x * v[i].x + v[i].y * v[i].y + v[i].z * v[i].z + v[i].w * v[i].w;
  }
#pragma unroll
  for (int m = 1; m < 64; m <<= 1) { s += __shfl_xor(s, m); s2 += __shfl_xor(s2, m); }
  const float mu = s * (1.0f / E_DIM);
  const float var = s2 * (1.0f / E_DIM) - mu * mu;
  const float rstd = rsqrtf(var + 1e-5f);
  __hip_bfloat16* orow = out + (size_t)row * E_DIM;
#pragma unroll
  for (int i = 0; i < 4; ++i) {
    const int col = (i * 64 + lane) * 4;
    const float4 gv = *reinterpret_cast<const float4*>(&g[col]);
    const float4 bv = *reinterpret_cast<const float4*>(&bb[col]);
    ushort4 pk;
    pk.x = f2bfbits((v[i].x - mu) * rstd * gv.x + bv.x);
    pk.y = f2bfbits((v[i].y - mu) * rstd * gv.y + bv.y);
    pk.z = f2bfbits((v[i].z - mu) * rstd * gv.z + bv.z);
    pk.w = f2bfbits((v[i].w - mu) * rstd * gv.w + bv.w);
    *reinterpret_cast<ushort4*>(&orow[col]) = pk;
  }
}

// ---------------- 128^2 bf16 GEMM, T2-swizzled LDS, 3 waves/EU ----------------
// QKV_MODE: Q cols scaled by 0.125*log2e (base-2 softmax downstream); V cols
// written TRANSPOSED to vt[b][h][d][T]; K cols written normally to outB.
template <int GELU_ACT, int ADD_RES, int OUT_F32, int QKV_MODE>
__global__ __launch_bounds__(256, 3) void gemm_bt(
    const __hip_bfloat16* __restrict__ A, const __hip_bfloat16* __restrict__ Bt,
    const float* __restrict__ bias, const float* __restrict__ res,
    float* __restrict__ outF, __hip_bfloat16* __restrict__ outB,
    __hip_bfloat16* __restrict__ vt,
    int M, int N, int K) {
  __shared__ __hip_bfloat16 sA[2][128 * 32];
  __shared__ __hip_bfloat16 sB[2][128 * 32];
  const int tid = threadIdx.x;
  const int w = tid >> 6, l = tid & 63;
  const int lhi = l >> 4, llo = l & 15;
  const int gx = gridDim.x;
  int wg = blockIdx.y * gx + blockIdx.x;
  const int cpx = (gx * gridDim.y) >> 3;
  wg = (wg & 7) * cpx + (wg >> 3);
  const int m0 = (wg / gx) * 128, n0 = (wg % gx) * 128;
  const int wr = (w >> 1) * 64, wc = (w & 1) * 64;
  f32x4 acc[4][4];
#pragma unroll
  for (int i = 0; i < 4; ++i)
#pragma unroll
    for (int j = 0; j < 4; ++j) acc[i][j] = zero4();

  const int nt = K >> 5;
  const int cswz = (((tid & 3) ^ ((tid >> 2) & 3)) << 3);
  auto stage = [&](int buf, int t) {
    const int k0 = t << 5;
#pragma unroll
    for (int i = 0; i < 2; ++i) {
      const int r = i * 64 + (tid >> 2);
      const int e = i * 2048 + tid * 8;
      __builtin_amdgcn_global_load_lds(
          (const __attribute__((address_space(1))) void*)(A + (size_t)(m0 + r) * K + k0 + cswz),
          (__attribute__((address_space(3))) void*)(&sA[buf][e]), 16, 0, 0);
      __builtin_amdgcn_global_load_lds(
          (const __attribute__((address_space(1))) void*)(Bt + (size_t)(n0 + r) * K + k0 + cswz),
          (__attribute__((address_space(3))) void*)(&sB[buf][e]), 16, 0, 0);
    }
  };

  stage(0, 0);
  for (int t = 0; t < nt; ++t) {
    const int cur = t & 1;
    __syncthreads();
    if (t + 1 < nt) stage(cur ^ 1, t + 1);
    const __hip_bfloat16* pa = sA[cur];
    const __hip_bfloat16* pb = sB[cur];
    short8 af[4], bfr[4];
    const int gsw = (lhi ^ (llo & 3)) << 3;
#pragma unroll
    for (int i = 0; i < 4; ++i) {
      af[i]  = *reinterpret_cast<const short8*>(pa + (wr + i * 16 + llo) * 32 + gsw);
      bfr[i] = *reinterpret_cast<const short8*>(pb + (wc + i * 16 + llo) * 32 + gsw);
    }
#pragma unroll
    for (int mi = 0; mi < 4; ++mi)
#pragma unroll
      for (int ni = 0; ni < 4; ++ni)
        acc[mi][ni] = __builtin_amdgcn_mfma_f32_16x16x32_bf16(af[mi], bfr[ni], acc[mi][ni], 0, 0, 0);
  }

#pragma unroll
  for (int mi = 0; mi < 4; ++mi) {
#pragma unroll
    for (int ni = 0; ni < 4; ++ni) {
      const int row = m0 + wr + mi * 16 + lhi * 4;
      const int col = n0 + wc + ni * 16 + llo;
      const float bc = bias[col];
      if (QKV_MODE) {
        const int r192 = col % 192;
        if (r192 >= 128) {
          // V column: write transposed to vt[b][h][d][T] (4 consecutive t = 8B)
          const int hh = col / 192, d = r192 - 128;
          const int bb2 = row >> 11, tr = row & 2047;
          ushort4 pk;
          pk.x = f2bfbits(acc[mi][ni][0] + bc);
          pk.y = f2bfbits(acc[mi][ni][1] + bc);
          pk.z = f2bfbits(acc[mi][ni][2] + bc);
          pk.w = f2bfbits(acc[mi][ni][3] + bc);
          *reinterpret_cast<ushort4*>(
              &vt[((size_t)(bb2 * NH + hh) * 64 + d) * T_DIM + tr]) = pk;
          continue;
        }
        const float qs = (r192 < 64) ? 0.18033688f : 1.0f;  // 0.125*log2(e) for Q
#pragma unroll
        for (int j = 0; j < 4; ++j)
          outB[(size_t)(row + j) * N + col] = __float2bfloat16((acc[mi][ni][j] + bc) * qs);
      } else {
#pragma unroll
        for (int j = 0; j < 4; ++j) {
          float v = acc[mi][ni][j] + bc;
          if (GELU_ACT) v = gelu_tanh(v);
          if (ADD_RES) v += res[(size_t)(row + j) * N + col];
          if (OUT_F32) outF[(size_t)(row + j) * N + col] = v;
          else outB[(size_t)(row + j) * N + col] = __float2bfloat16(v);
        }
      }
    }
  }
}

// ---------------- 64x128 bf16 GEMM for N=1024 outputs ----------------
template <int ADD_RES, int OUT_F32>
__global__ __launch_bounds__(256, 3) void gemm_small(
    const __hip_bfloat16* __restrict__ A, const __hip_bfloat16* __restrict__ Bt,
    const float* __restrict__ bias, const float* __restrict__ res,
    float* __restrict__ outF, __hip_bfloat16* __restrict__ outB,
    int M, int N, int K) {
  __shared__ __hip_bfloat16 sA[2][64 * 32];
  __shared__ __hip_bfloat16 sB[2][128 * 32];
  const int tid = threadIdx.x;
  const int w = tid >> 6, l = tid & 63;
  const int lhi = l >> 4, llo = l & 15;
  const int gx = gridDim.x;
  int wg = blockIdx.y * gx + blockIdx.x;
  const int cpx = (gx * gridDim.y) >> 3;
  wg = (wg & 7) * cpx + (wg >> 3);
  const int m0 = (wg / gx) * 64, n0 = (wg % gx) * 128;
  const int wr = (w >> 1) * 32, wc = (w & 1) * 64;
  f32x4 acc[2][4];
#pragma unroll
  for (int i = 0; i < 2; ++i)
#pragma unroll
    for (int j = 0; j < 4; ++j) acc[i][j] = zero4();

  const int nt = K >> 5;
  const int cswz = (((tid & 3) ^ ((tid >> 2) & 3)) << 3);
  auto stage = [&](int buf, int t) {
    const int k0 = t << 5;
    {
      const int r = tid >> 2;
      const int e = tid * 8;
      __builtin_amdgcn_global_load_lds(
          (const __attribute__((address_space(1))) void*)(A + (size_t)(m0 + r) * K + k0 + cswz),
          (__attribute__((address_space(3))) void*)(&sA[buf][e]), 16, 0, 0);
    }
#pragma unroll
    for (int i = 0; i < 2; ++i) {
      const int r = i * 64 + (tid >> 2);
      const int e = i * 2048 + tid * 8;
      __builtin_amdgcn_global_load_lds(
          (const __attribute__((address_space(1))) void*)(Bt + (size_t)(n0 + r) * K + k0 + cswz),
          (__attribute__((address_space(3))) void*)(&sB[buf][e]), 16, 0, 0);
    }
  };

  stage(0, 0);
  for (int t = 0; t < nt; ++t) {
    const int cur = t & 1;
    __syncthreads();
    if (t + 1 < nt) stage(cur ^ 1, t + 1);
    const __hip_bfloat16* pa = sA[cur];
    const __hip_bfloat16* pb = sB[cur];
    short8 af[2], bfr[4];
    const int gsw = (lhi ^ (llo & 3)) << 3;
#pragma unroll
    for (int i = 0; i < 2; ++i)
      af[i] = *reinterpret_cast<const short8*>(pa + (wr + i * 16 + llo) * 32 + gsw);
#pragma unroll
    for (int i = 0; i < 4; ++i)
      bfr[i] = *reinterpret_cast<const short8*>(pb + (wc + i * 16 + llo) * 32 + gsw);
#pragma unroll
    for (int mi = 0; mi < 2; ++mi)
#pragma unroll
      for (int ni = 0; ni < 4; ++ni)
        acc[mi][ni] = __builtin_amdgcn_mfma_f32_16x16x32_bf16(af[mi], bfr[ni], acc[mi][ni], 0, 0, 0);
  }

#pragma unroll
  for (int mi = 0; mi < 2; ++mi) {
#pragma unroll
    for (int ni = 0; ni < 4; ++ni) {
      const int row = m0 + wr + mi * 16 + lhi * 4;
      const int col = n0 + wc + ni * 16 + llo;
      const float bc = bias[col];
#pragma unroll
      for (int j = 0; j < 4; ++j) {
        float v = acc[mi][ni][j] + bc;
        if (ADD_RES) v += res[(size_t)(row + j) * N + col];
        if (OUT_F32) outF[(size_t)(row + j) * N + col] = v;
        else outB[(size_t)(row + j) * N + col] = __float2bfloat16(v);
      }
    }
  }
}

// ---------------- causal flash attention v16: kv-tile pairs -------------------
// v14/v15 structure (1 q-tile/block, 4 waves = 4 kv-quarters, heavy-first,
// (256,3), no-max base-2 softmax, plain-sum merge). New: kv-tiles processed in
// PAIRS: one lgkmcnt drain per 2 tiles, QK(b) overlaps exp(a), both K loads
// issue together. sP doubled to [4][2][32][72] (36.9KB; 3 blocks/CU = 110KB).
// In the pair loop tile a is never the diagonal tile (kt < nkv-1 guaranteed).
// All buffers straight-line named arrays, literal slot indices (no lambdas).

#define ATTN_LDK(KB, K0v)                                                      \
  _Pragma("unroll") for (int ni = 0; ni < 4; ++ni) {                           \
    const __hip_bfloat16* kp =                                                 \
        qkv + ((rb + (K0v) + ni * 16 + llo) * 3072 + h * 192 + 64 + lhi * 8);  \
    KB[ni][0] = *reinterpret_cast<const short8*>(kp);                          \
    KB[ni][1] = *reinterpret_cast<const short8*>(kp + 32);                     \
  }

#define ATTN_LDV(VB, K0v)                                                      \
  _Pragma("unroll") for (int di = 0; di < 4; ++di) {                           \
    const __hip_bfloat16* vp =                                                 \
        vt + (vbase + (size_t)(di * 16 + llo) * T_DIM + (K0v) + lhi * 8);      \
    VB[di][0] = *reinterpret_cast<const short8*>(vp);                          \
    VB[di][1] = *reinterpret_cast<const short8*>(vp + 32);                     \
  }

#define ATTN_QK(SC, QFA, QFB, KB, SKIP)                                        \
  _Pragma("unroll") for (int ni = 0; ni < 4; ++ni) {                           \
    SC[ni] = zero4();                                                          \
    if (!(SKIP) || ni < 2) {                                                   \
      SC[ni] = __builtin_amdgcn_mfma_f32_16x16x32_bf16(QFA, KB[ni][0], SC[ni], 0, 0, 0); \
      SC[ni] = __builtin_amdgcn_mfma_f32_16x16x32_bf16(QFB, KB[ni][1], SC[ni], 0, 0, 0); \
    }                                                                          \
  }

#define ATTN_EXP(SC, MFv, SLOT, DIAGv)                                         \
  _Pragma("unroll") for (int j = 0; j < 4; ++j) {                              \
    const int ql = (MFv) * 16 + lhi * 4 + j;                                   \
    _Pragma("unroll") for (int ni = 0; ni < 4; ++ni) {                         \
      float sval = SC[ni][j];                                                  \
      if (DIAGv) sval = (ni * 16 + llo <= base + ql) ? sval : -1e30f;          \
      sP[s4][SLOT][(MFv) * 16 + lhi * 4 + j][ni * 16 + llo] =                  \
          __float2bfloat16(exp2f(sval));                                       \
    }                                                                          \
  }

#define ATTN_PV(SLOT, VB, EVv)                                                 \
  _Pragma("unroll") for (int mf = 0; mf < 2; ++mf) {                           \
    const short8 pf0 =                                                         \
        *reinterpret_cast<const short8*>(&sP[s4][SLOT][mf * 16 + llo][lhi * 8]);      \
    const short8 pf1 =                                                         \
        *reinterpret_cast<const short8*>(&sP[s4][SLOT][mf * 16 + llo][32 + lhi * 8]); \
    f32x4 lacc = zero4();                                                      \
    lacc = __builtin_amdgcn_mfma_f32_16x16x32_bf16(pf0, onesb, lacc, 0, 0, 0); \
    if (!(EVv)) lacc = __builtin_amdgcn_mfma_f32_16x16x32_bf16(pf1, onesb, lacc, 0, 0, 0); \
    _Pragma("unroll") for (int di = 0; di < 4; ++di) {                         \
      oacc[mf][di] =                                                           \
          __builtin_amdgcn_mfma_f32_16x16x32_bf16(pf0, VB[di][0], oacc[mf][di], 0, 0, 0); \
      if (!(EVv))                                                              \
        oacc[mf][di] =                                                         \
            __builtin_amdgcn_mfma_f32_16x16x32_bf16(pf1, VB[di][1], oacc[mf][di], 0, 0, 0); \
    }                                                                          \
    _Pragma("unroll") for (int j = 0; j < 4; ++j) lrun[mf][j] += lacc[j];      \
  }

__global__ __launch_bounds__(256, 3) void attn_fwd(
    const __hip_bfloat16* __restrict__ qkv, const __hip_bfloat16* __restrict__ vt,
    __hip_bfloat16* __restrict__ aout) {
  const int hb = blockIdx.x;
  const int h = hb & 15, b = hb >> 4;
  const int tid = threadIdx.x, s4 = tid >> 6, l = tid & 63;
  const int lhi = l >> 4, llo = l & 15;
  const int tile = 63 - (int)blockIdx.y;  // heavy-first
  const size_t rb = (size_t)b * T_DIM;
  const size_t vbase = ((size_t)(b * NH + h) * 64) * T_DIM;
  __shared__ __align__(16) unsigned char smem[36864];  // sP 36864 >= merge 16128
  auto sP = reinterpret_cast<__hip_bfloat16(*)[2][32][72]>(smem);  // [4][2][32][72]
  float* mrgf = reinterpret_cast<float*>(smem);  // merge view: (s*64+l)*21 floats

  short8 onesb;
#pragma unroll
  for (int i = 0; i < 8; ++i) onesb[i] = (short)0x3F80;  // bf16 1.0

  const int q0 = tile * 32;
  const int nkv = (tile >> 1) + 1;       // kv-tiles of 64
  const int base = (tile & 1) << 5;      // diag offset: 0 or 32
  const int kt_begin = (s4 * nkv) >> 2;
  const int kt_end   = ((s4 + 1) * nkv) >> 2;

  short8 qf[2][2];
#pragma unroll
  for (int mf = 0; mf < 2; ++mf) {
    const __hip_bfloat16* qp =
        qkv + ((rb + q0 + mf * 16 + llo) * 3072 + h * 192 + lhi * 8);
    qf[mf][0] = *reinterpret_cast<const short8*>(qp);
    qf[mf][1] = *reinterpret_cast<const short8*>(qp + 32);
  }
  float lrun[2][4];
  f32x4 oacc[2][4];
#pragma unroll
  for (int mf = 0; mf < 2; ++mf)
#pragma unroll
    for (int j = 0; j < 4; ++j) lrun[mf][j] = 0.f;
#pragma unroll
  for (int mf = 0; mf < 2; ++mf)
#pragma unroll
    for (int di = 0; di < 4; ++di) oacc[mf][di] = zero4();

  int kt = kt_begin;
  // ---- pair loop: tiles (kt, kt+1); tile a is never the diagonal tile ----
  for (; kt + 1 < kt_end; kt += 2) {
    const int k0a = kt * 64, k0b = k0a + 64;
    const bool dgb = (kt + 1 == nkv - 1);
    const bool evb = dgb && (base == 0);
    short8 kA[4][2], kB[4][2];
    ATTN_LDK(kA, k0a)
    ATTN_LDK(kB, k0b)
    f32x4 scA0[4], scA1[4], scB0[4], scB1[4];
    __builtin_amdgcn_s_setprio(1);
    ATTN_QK(scA0, qf[0][0], qf[0][1], kA, false)
    ATTN_QK(scA1, qf[1][0], qf[1][1], kA, false)
    __builtin_amdgcn_s_setprio(0);
    ATTN_EXP(scA0, 0, 0, false)
    __builtin_amdgcn_s_setprio(1);
    ATTN_QK(scB0, qf[0][0], qf[0][1], kB, evb)
    __builtin_amdgcn_s_setprio(0);
    ATTN_EXP(scA1, 1, 0, false)
    __builtin_amdgcn_s_setprio(1);
    ATTN_QK(scB1, qf[1][0], qf[1][1], kB, evb)
    __builtin_amdgcn_s_setprio(0);
    short8 vA[4][2], vB[4][2];
    ATTN_LDV(vA, k0a)
    ATTN_LDV(vB, k0b)
    ATTN_EXP(scB0, 0, 1, dgb)
    ATTN_EXP(scB1, 1, 1, dgb)
    asm volatile("s_waitcnt lgkmcnt(0)" ::: "memory");  // P writes -> P reads
    __builtin_amdgcn_s_setprio(1);
    ATTN_PV(0, vA, false)
    ATTN_PV(1, vB, evb)
    __builtin_amdgcn_s_setprio(0);
  }
  // ---- tail: single tile ----
  if (kt < kt_end) {
    const int k0 = kt * 64;
    const bool diag = (kt == nkv - 1);
    const bool evd = diag && (base == 0);
    short8 kA[4][2];
    ATTN_LDK(kA, k0)
    f32x4 sc0[4], sc1[4];
    __builtin_amdgcn_s_setprio(1);
    ATTN_QK(sc0, qf[0][0], qf[0][1], kA, evd)
    ATTN_QK(sc1, qf[1][0], qf[1][1], kA, evd)
    __builtin_amdgcn_s_setprio(0);
    short8 vA[4][2];
    ATTN_LDV(vA, k0)
    ATTN_EXP(sc0, 0, 0, diag)
    ATTN_EXP(sc1, 1, 0, diag)
    asm volatile("s_waitcnt lgkmcnt(0)" ::: "memory");
    __builtin_amdgcn_s_setprio(1);
    ATTN_PV(0, vA, evd)
    __builtin_amdgcn_s_setprio(0);
  }

  // ---- 4-way merge: plain sums. s=0..2 stage partials, s=3 combines.
  // Stride 21 floats/lane: odd -> conflict-free across 32 banks.
#pragma unroll
  for (int mf = 0; mf < 2; ++mf) {
    __syncthreads();  // sP reads done / prior phase consumed
    if (s4 < 3) {
      float* dst = mrgf + (s4 * 64 + l) * 21;
#pragma unroll
      for (int di = 0; di < 4; ++di)
#pragma unroll
        for (int j = 0; j < 4; ++j) dst[di * 4 + j] = oacc[mf][di][j];
#pragma unroll
      for (int j = 0; j < 4; ++j) dst[16 + j] = lrun[mf][j];
    }
    __syncthreads();
    if (s4 == 3) {
#pragma unroll
      for (int j = 0; j < 4; ++j) {
        float lt = lrun[mf][j];
#pragma unroll
        for (int si = 0; si < 3; ++si) lt += mrgf[(si * 64 + l) * 21 + 16 + j];
        const float inv = 1.0f / lt;
        const size_t row = rb + q0 + mf * 16 + lhi * 4 + j;
#pragma unroll
        for (int di = 0; di < 4; ++di) {
          float o = oacc[mf][di][j];
#pragma unroll
          for (int si = 0; si < 3; ++si) o += mrgf[(si * 64 + l) * 21 + di * 4 + j];
          aout[row * 1024 + h * 64 + di * 16 + llo] = __float2bfloat16(o * inv);
        }
      }
    }
  }
}

// ---------------- launch ----------------
extern "C" void kernel_launch(void* const* d_in, const int* in_sizes, int n_in,
                              void* d_out, int out_size, void* d_ws, size_t ws_size,
                              hipStream_t stream) {
  (void)in_sizes; (void)n_in; (void)out_size; (void)ws_size;
  const float* x      = (const float*)d_in[0];
  const float* ln1_g  = (const float*)d_in[1];
  const float* ln1_b  = (const float*)d_in[2];
  const float* w_qkv  = (const float*)d_in[3];
  const float* b_qkv  = (const float*)d_in[4];
  const float* w_out  = (const float*)d_in[5];
  const float* b_out  = (const float*)d_in[6];
  const float* ln2_g  = (const float*)d_in[7];
  const float* ln2_b  = (const float*)d_in[8];
  const float* w_fc   = (const float*)d_in[9];
  const float* b_fc   = (const float*)d_in[10];
  const float* w_proj = (const float*)d_in[11];
  const float* b_proj = (const float*)d_in[12];
  float* out = (float*)d_out;

  const int M = 2 * T_DIM;  // 4096 rows
  char* wsp = (char*)d_ws;
  size_t off = 0;
  auto carve = [&](size_t bytes) {
    void* p = wsp + off;
    off += (bytes + 255) & ~(size_t)255;
    return p;
  };
  __hip_bfloat16* wt_qkv  = (__hip_bfloat16*)carve((size_t)3072 * 1024 * 2);
  __hip_bfloat16* wt_out  = (__hip_bfloat16*)carve((size_t)1024 * 1024 * 2);
  __hip_bfloat16* wt_fc   = (__hip_bfloat16*)carve((size_t)4096 * 1024 * 2);
  __hip_bfloat16* wt_proj = (__hip_bfloat16*)carve((size_t)1024 * 4096 * 2);
  __hip_bfloat16* ln1o    = (__hip_bfloat16*)carve((size_t)M * 1024 * 2);
  __hip_bfloat16* qkvb    = (__hip_bfloat16*)carve((size_t)M * 3072 * 2);
  __hip_bfloat16* vtb     = (__hip_bfloat16*)carve((size_t)2 * NH * 64 * T_DIM * 2);
  __hip_bfloat16* attnb   = (__hip_bfloat16*)carve((size_t)M * 1024 * 2);
  float*          x2      = (float*)carve((size_t)M * 1024 * 4);
  __hip_bfloat16* h1      = (__hip_bfloat16*)carve((size_t)M * 4096 * 2);
  __hip_bfloat16* ln2o    = ln1o;  // ln1 output dead after QKV GEMM; reuse

  // fused prologue: 4 weight transposes + LN1 in one launch
  prep<<<4096, 256, 0, stream>>>(w_qkv, w_out, w_fc, w_proj,
                                 wt_qkv, wt_out, wt_fc, wt_proj,
                                 x, ln1_g, ln1_b, ln1o);
  gemm_bt<0, 0, 0, 1><<<dim3(3072 / 128, M / 128), 256, 0, stream>>>(
      ln1o, wt_qkv, b_qkv, nullptr, nullptr, qkvb, vtb, M, 3072, 1024);
  attn_fwd<<<dim3(32, 64), 256, 0, stream>>>(qkvb, vtb, attnb);
  gemm_small<1, 1><<<dim3(1024 / 128, M / 64), 256, 0, stream>>>(
      attnb, wt_out, b_out, x, x2, nullptr, M, 1024, 1024);
  layernorm_bf16<<<M / 4, 256, 0, stream>>>(x2, ln2_g, ln2_b, ln2o);
  gemm_bt<1, 0, 0, 0><<<dim3(4096 / 128, M / 128), 256, 0, stream>>>(
      ln2o, wt_fc, b_fc, nullptr, nullptr, h1, nullptr, M, 4096, 1024);
  gemm_small<1, 1><<<dim3(1024 / 128, M / 64), 256, 0, stream>>>(
      h1, wt_proj, b_proj, x2, out, nullptr, M, 1024, 4096);
}

// Round 28
// 257.649 us; speedup vs baseline: 1.0496x; 1.0496x over previous
//
#include <hip/hip_runtime.h>
#include <hip/hip_bf16.h>

// Transformer block forward: B=2, T=2048, E=1024, H=16, D=64.
// Pipeline: prep (transposes+LN1) | QKV GEMM (128^2 swz, V written transposed
//           in epilogue, Q pre-scaled by 0.125*log2e) | flash attn v15
//           (no-max base-2 softmax + next-K prefetch into dead kC regs) |
//           out-proj+res (64x128) | LN2 | FC+GELU (128^2) | proj+res (64x128).

#define T_DIM 2048
#define E_DIM 1024
#define NH 16

using short8 = __attribute__((__ext_vector_type__(8))) short;
using f32x4  = __attribute__((__ext_vector_type__(4))) float;

static __device__ __forceinline__ f32x4 zero4() {
  f32x4 z = {0.f, 0.f, 0.f, 0.f};
  return z;
}

static __device__ __forceinline__ unsigned short f2bfbits(float f) {
  __hip_bfloat16 h = __float2bfloat16(f);
  return *reinterpret_cast<unsigned short*>(&h);
}

static __device__ __forceinline__ float gelu_tanh(float x) {
  float z = 0.7978845608028654f * (x + 0.044715f * x * x * x);
  float e = __expf(2.0f * z);
  float th = 1.0f - 2.0f / (e + 1.0f);
  return 0.5f * x * (1.0f + th);
}

// ---------------- prep: 4 weight transposes (f32 [K][N] -> bf16 [N][K]) + LN1 ----
__global__ __launch_bounds__(256) void prep(
    const float* __restrict__ w_qkv, const float* __restrict__ w_out,
    const float* __restrict__ w_fc, const float* __restrict__ w_proj,
    __hip_bfloat16* __restrict__ t_qkv, __hip_bfloat16* __restrict__ t_out,
    __hip_bfloat16* __restrict__ t_fc, __hip_bfloat16* __restrict__ t_proj,
    const float* __restrict__ x, const float* __restrict__ g,
    const float* __restrict__ bb, __hip_bfloat16* __restrict__ ln1o) {
  __shared__ float tl[64][65];
  const int id = blockIdx.x;
  const int t = threadIdx.x;
  if (id < 3072) {
    const float* in;
    __hip_bfloat16* out;
    int K, N, bx, by;
    if (id < 768) {
      in = w_qkv; out = t_qkv; K = 1024; N = 3072; bx = id % 48; by = id / 48;
    } else if (id < 1024) {
      const int i = id - 768;
      in = w_out; out = t_out; K = 1024; N = 1024; bx = i % 16; by = i / 16;
    } else if (id < 2048) {
      const int i = id - 1024;
      in = w_fc; out = t_fc; K = 1024; N = 4096; bx = i % 64; by = i / 64;
    } else {
      const int i = id - 2048;
      in = w_proj; out = t_proj; K = 4096; N = 1024; bx = i % 16; by = i / 16;
    }
    const int n0 = bx * 64, k0 = by * 64;
    const int rr = t >> 4;        // 0..15
    const int cc = (t & 15) * 4;  // 0..60
#pragma unroll
    for (int i = 0; i < 4; ++i) {
      const int row = rr + i * 16;
      const float4 v = *reinterpret_cast<const float4*>(&in[(size_t)(k0 + row) * N + n0 + cc]);
      tl[row][cc] = v.x; tl[row][cc + 1] = v.y; tl[row][cc + 2] = v.z; tl[row][cc + 3] = v.w;
    }
    __syncthreads();
#pragma unroll
    for (int i = 0; i < 4; ++i) {
      const int row = rr + i * 16;  // output row (n)
      ushort4 pk;
      pk.x = f2bfbits(tl[cc + 0][row]);
      pk.y = f2bfbits(tl[cc + 1][row]);
      pk.z = f2bfbits(tl[cc + 2][row]);
      pk.w = f2bfbits(tl[cc + 3][row]);
      *reinterpret_cast<ushort4*>(&out[(size_t)(n0 + row) * K + k0 + cc]) = pk;
    }
  } else {
    // LN1
    const int lane = t & 63;
    const int row = (id - 3072) * 4 + (t >> 6);
    const float* xr = x + (size_t)row * E_DIM;
    float4 v[4];
    float s = 0.f, s2 = 0.f;
#pragma unroll
    for (int i = 0; i < 4; ++i) {
      v[i] = *reinterpret_cast<const float4*>(&xr[(i * 64 + lane) * 4]);
      s  += v[i].x + v[i].y + v[i].z + v[i].w;
      s2 += v[i].x * v[i].x + v[i].y * v[i].y + v[i].z * v[i].z + v[i].w * v[i].w;
    }
#pragma unroll
    for (int m = 1; m < 64; m <<= 1) { s += __shfl_xor(s, m); s2 += __shfl_xor(s2, m); }
    const float mu = s * (1.0f / E_DIM);
    const float var = s2 * (1.0f / E_DIM) - mu * mu;
    const float rstd = rsqrtf(var + 1e-5f);
    __hip_bfloat16* orow = ln1o + (size_t)row * E_DIM;
#pragma unroll
    for (int i = 0; i < 4; ++i) {
      const int col = (i * 64 + lane) * 4;
      const float4 gv = *reinterpret_cast<const float4*>(&g[col]);
      const float4 bv = *reinterpret_cast<const float4*>(&bb[col]);
      ushort4 pk;
      pk.x = f2bfbits((v[i].x - mu) * rstd * gv.x + bv.x);
      pk.y = f2bfbits((v[i].y - mu) * rstd * gv.y + bv.y);
      pk.z = f2bfbits((v[i].z - mu) * rstd * gv.z + bv.z);
      pk.w = f2bfbits((v[i].w - mu) * rstd * gv.w + bv.w);
      *reinterpret_cast<ushort4*>(&orow[col]) = pk;
    }
  }
}

// ---------------- LayerNorm rows of 1024, f32 in -> bf16 out (LN2) ----------------
__global__ __launch_bounds__(256) void layernorm_bf16(
    const float* __restrict__ x, const float* __restrict__ g, const float* __restrict__ bb,
    __hip_bfloat16* __restrict__ out) {
  const int lane = threadIdx.x & 63;
  const int row = blockIdx.x * 4 + (threadIdx.x >> 6);
  const float* xr = x + (size_t)row * E_DIM;
  float4 v[4];
  float s = 0.f, s2 = 0.f;
#pragma unroll
  for (int i = 0; i < 4; ++i) {
    v[i] = *reinterpret_cast<const float4*>(&xr[(i * 64 + lane) * 4]);
    s  += v[i].x + v[i].y + v[i].z + v[i].w;
    s2 += v[i].x * v[i].x + v[i].y * v[i].y + v[i].z * v[i].z + v[i].w * v[i].w;
  }
#pragma unroll
  for (int m = 1; m < 64; m <<= 1) { s += __shfl_xor(s, m); s2 += __shfl_xor(s2, m); }
  const float mu = s * (1.0f / E_DIM);
  const float var = s2 * (1.0f / E_DIM) - mu * mu;
  const float rstd = rsqrtf(var + 1e-5f);
  __hip_bfloat16* orow = out + (size_t)row * E_DIM;
#pragma unroll
  for (int i = 0; i < 4; ++i) {
    const int col = (i * 64 + lane) * 4;
    const float4 gv = *reinterpret_cast<const float4*>(&g[col]);
    const float4 bv = *reinterpret_cast<const float4*>(&bb[col]);
    ushort4 pk;
    pk.x = f2bfbits((v[i].x - mu) * rstd * gv.x + bv.x);
    pk.y = f2bfbits((v[i].y - mu) * rstd * gv.y + bv.y);
    pk.z = f2bfbits((v[i].z - mu) * rstd * gv.z + bv.z);
    pk.w = f2bfbits((v[i].w - mu) * rstd * gv.w + bv.w);
    *reinterpret_cast<ushort4*>(&orow[col]) = pk;
  }
}

// ---------------- 128^2 bf16 GEMM, T2-swizzled LDS, 3 waves/EU ----------------
// QKV_MODE: Q cols scaled by 0.125*log2e (base-2 softmax downstream); V cols
// written TRANSPOSED to vt[b][h][d][T]; K cols written normally to outB.
template <int GELU_ACT, int ADD_RES, int OUT_F32, int QKV_MODE>
__global__ __launch_bounds__(256, 3) void gemm_bt(
    const __hip_bfloat16* __restrict__ A, const __hip_bfloat16* __restrict__ Bt,
    const float* __restrict__ bias, const float* __restrict__ res,
    float* __restrict__ outF, __hip_bfloat16* __restrict__ outB,
    __hip_bfloat16* __restrict__ vt,
    int M, int N, int K) {
  __shared__ __hip_bfloat16 sA[2][128 * 32];
  __shared__ __hip_bfloat16 sB[2][128 * 32];
  const int tid = threadIdx.x;
  const int w = tid >> 6, l = tid & 63;
  const int lhi = l >> 4, llo = l & 15;
  const int gx = gridDim.x;
  int wg = blockIdx.y * gx + blockIdx.x;
  const int cpx = (gx * gridDim.y) >> 3;
  wg = (wg & 7) * cpx + (wg >> 3);
  const int m0 = (wg / gx) * 128, n0 = (wg % gx) * 128;
  const int wr = (w >> 1) * 64, wc = (w & 1) * 64;
  f32x4 acc[4][4];
#pragma unroll
  for (int i = 0; i < 4; ++i)
#pragma unroll
    for (int j = 0; j < 4; ++j) acc[i][j] = zero4();

  const int nt = K >> 5;
  const int cswz = (((tid & 3) ^ ((tid >> 2) & 3)) << 3);
  auto stage = [&](int buf, int t) {
    const int k0 = t << 5;
#pragma unroll
    for (int i = 0; i < 2; ++i) {
      const int r = i * 64 + (tid >> 2);
      const int e = i * 2048 + tid * 8;
      __builtin_amdgcn_global_load_lds(
          (const __attribute__((address_space(1))) void*)(A + (size_t)(m0 + r) * K + k0 + cswz),
          (__attribute__((address_space(3))) void*)(&sA[buf][e]), 16, 0, 0);
      __builtin_amdgcn_global_load_lds(
          (const __attribute__((address_space(1))) void*)(Bt + (size_t)(n0 + r) * K + k0 + cswz),
          (__attribute__((address_space(3))) void*)(&sB[buf][e]), 16, 0, 0);
    }
  };

  stage(0, 0);
  for (int t = 0; t < nt; ++t) {
    const int cur = t & 1;
    __syncthreads();
    if (t + 1 < nt) stage(cur ^ 1, t + 1);
    const __hip_bfloat16* pa = sA[cur];
    const __hip_bfloat16* pb = sB[cur];
    short8 af[4], bfr[4];
    const int gsw = (lhi ^ (llo & 3)) << 3;
#pragma unroll
    for (int i = 0; i < 4; ++i) {
      af[i]  = *reinterpret_cast<const short8*>(pa + (wr + i * 16 + llo) * 32 + gsw);
      bfr[i] = *reinterpret_cast<const short8*>(pb + (wc + i * 16 + llo) * 32 + gsw);
    }
#pragma unroll
    for (int mi = 0; mi < 4; ++mi)
#pragma unroll
      for (int ni = 0; ni < 4; ++ni)
        acc[mi][ni] = __builtin_amdgcn_mfma_f32_16x16x32_bf16(af[mi], bfr[ni], acc[mi][ni], 0, 0, 0);
  }

#pragma unroll
  for (int mi = 0; mi < 4; ++mi) {
#pragma unroll
    for (int ni = 0; ni < 4; ++ni) {
      const int row = m0 + wr + mi * 16 + lhi * 4;
      const int col = n0 + wc + ni * 16 + llo;
      const float bc = bias[col];
      if (QKV_MODE) {
        const int r192 = col % 192;
        if (r192 >= 128) {
          // V column: write transposed to vt[b][h][d][T] (4 consecutive t = 8B)
          const int hh = col / 192, d = r192 - 128;
          const int bb2 = row >> 11, tr = row & 2047;
          ushort4 pk;
          pk.x = f2bfbits(acc[mi][ni][0] + bc);
          pk.y = f2bfbits(acc[mi][ni][1] + bc);
          pk.z = f2bfbits(acc[mi][ni][2] + bc);
          pk.w = f2bfbits(acc[mi][ni][3] + bc);
          *reinterpret_cast<ushort4*>(
              &vt[((size_t)(bb2 * NH + hh) * 64 + d) * T_DIM + tr]) = pk;
          continue;
        }
        const float qs = (r192 < 64) ? 0.18033688f : 1.0f;  // 0.125*log2(e) for Q
#pragma unroll
        for (int j = 0; j < 4; ++j)
          outB[(size_t)(row + j) * N + col] = __float2bfloat16((acc[mi][ni][j] + bc) * qs);
      } else {
#pragma unroll
        for (int j = 0; j < 4; ++j) {
          float v = acc[mi][ni][j] + bc;
          if (GELU_ACT) v = gelu_tanh(v);
          if (ADD_RES) v += res[(size_t)(row + j) * N + col];
          if (OUT_F32) outF[(size_t)(row + j) * N + col] = v;
          else outB[(size_t)(row + j) * N + col] = __float2bfloat16(v);
        }
      }
    }
  }
}

// ---------------- 64x128 bf16 GEMM for N=1024 outputs ----------------
template <int ADD_RES, int OUT_F32>
__global__ __launch_bounds__(256, 3) void gemm_small(
    const __hip_bfloat16* __restrict__ A, const __hip_bfloat16* __restrict__ Bt,
    const float* __restrict__ bias, const float* __restrict__ res,
    float* __restrict__ outF, __hip_bfloat16* __restrict__ outB,
    int M, int N, int K) {
  __shared__ __hip_bfloat16 sA[2][64 * 32];
  __shared__ __hip_bfloat16 sB[2][128 * 32];
  const int tid = threadIdx.x;
  const int w = tid >> 6, l = tid & 63;
  const int lhi = l >> 4, llo = l & 15;
  const int gx = gridDim.x;
  int wg = blockIdx.y * gx + blockIdx.x;
  const int cpx = (gx * gridDim.y) >> 3;
  wg = (wg & 7) * cpx + (wg >> 3);
  const int m0 = (wg / gx) * 64, n0 = (wg % gx) * 128;
  const int wr = (w >> 1) * 32, wc = (w & 1) * 64;
  f32x4 acc[2][4];
#pragma unroll
  for (int i = 0; i < 2; ++i)
#pragma unroll
    for (int j = 0; j < 4; ++j) acc[i][j] = zero4();

  const int nt = K >> 5;
  const int cswz = (((tid & 3) ^ ((tid >> 2) & 3)) << 3);
  auto stage = [&](int buf, int t) {
    const int k0 = t << 5;
    {
      const int r = tid >> 2;
      const int e = tid * 8;
      __builtin_amdgcn_global_load_lds(
          (const __attribute__((address_space(1))) void*)(A + (size_t)(m0 + r) * K + k0 + cswz),
          (__attribute__((address_space(3))) void*)(&sA[buf][e]), 16, 0, 0);
    }
#pragma unroll
    for (int i = 0; i < 2; ++i) {
      const int r = i * 64 + (tid >> 2);
      const int e = i * 2048 + tid * 8;
      __builtin_amdgcn_global_load_lds(
          (const __attribute__((address_space(1))) void*)(Bt + (size_t)(n0 + r) * K + k0 + cswz),
          (__attribute__((address_space(3))) void*)(&sB[buf][e]), 16, 0, 0);
    }
  };

  stage(0, 0);
  for (int t = 0; t < nt; ++t) {
    const int cur = t & 1;
    __syncthreads();
    if (t + 1 < nt) stage(cur ^ 1, t + 1);
    const __hip_bfloat16* pa = sA[cur];
    const __hip_bfloat16* pb = sB[cur];
    short8 af[2], bfr[4];
    const int gsw = (lhi ^ (llo & 3)) << 3;
#pragma unroll
    for (int i = 0; i < 2; ++i)
      af[i] = *reinterpret_cast<const short8*>(pa + (wr + i * 16 + llo) * 32 + gsw);
#pragma unroll
    for (int i = 0; i < 4; ++i)
      bfr[i] = *reinterpret_cast<const short8*>(pb + (wc + i * 16 + llo) * 32 + gsw);
#pragma unroll
    for (int mi = 0; mi < 2; ++mi)
#pragma unroll
      for (int ni = 0; ni < 4; ++ni)
        acc[mi][ni] = __builtin_amdgcn_mfma_f32_16x16x32_bf16(af[mi], bfr[ni], acc[mi][ni], 0, 0, 0);
  }

#pragma unroll
  for (int mi = 0; mi < 2; ++mi) {
#pragma unroll
    for (int ni = 0; ni < 4; ++ni) {
      const int row = m0 + wr + mi * 16 + lhi * 4;
      const int col = n0 + wc + ni * 16 + llo;
      const float bc = bias[col];
#pragma unroll
      for (int j = 0; j < 4; ++j) {
        float v = acc[mi][ni][j] + bc;
        if (ADD_RES) v += res[(size_t)(row + j) * N + col];
        if (OUT_F32) outF[(size_t)(row + j) * N + col] = v;
        else outB[(size_t)(row + j) * N + col] = __float2bfloat16(v);
      }
    }
  }
}

// ---------------- causal flash attention v15: no-max + next-K prefetch -------
// (round-26 verified best: 74.7us, VGPR 84, no spill)
__global__ __launch_bounds__(256, 3) void attn_fwd(
    const __hip_bfloat16* __restrict__ qkv, const __hip_bfloat16* __restrict__ vt,
    __hip_bfloat16* __restrict__ aout) {
  const int hb = blockIdx.x;
  const int h = hb & 15, b = hb >> 4;
  const int tid = threadIdx.x, s4 = tid >> 6, l = tid & 63;
  const int lhi = l >> 4, llo = l & 15;
  const int tile = 63 - (int)blockIdx.y;  // heavy-first
  const size_t rb = (size_t)b * T_DIM;
  const size_t vbase = ((size_t)(b * NH + h) * 64) * T_DIM;
  __shared__ __align__(16) unsigned char smem[18432];  // sP 18432 >= merge 16128
  auto sP = reinterpret_cast<__hip_bfloat16(*)[32][72]>(smem);   // [4][32][72]
  float* mrgf = reinterpret_cast<float*>(smem);  // merge view: (s*64+l)*21 floats

  short8 onesb;
#pragma unroll
  for (int i = 0; i < 8; ++i) onesb[i] = (short)0x3F80;  // bf16 1.0

  const int q0 = tile * 32;
  const int nkv = (tile >> 1) + 1;       // kv-tiles of 64
  const int base = (tile & 1) << 5;      // diag offset: 0 or 32
  const int kt_begin = (s4 * nkv) >> 2;
  const int kt_end   = ((s4 + 1) * nkv) >> 2;

  short8 qf[2][2];
#pragma unroll
  for (int mf = 0; mf < 2; ++mf) {
    const __hip_bfloat16* qp =
        qkv + ((rb + q0 + mf * 16 + llo) * 3072 + h * 192 + lhi * 8);
    qf[mf][0] = *reinterpret_cast<const short8*>(qp);
    qf[mf][1] = *reinterpret_cast<const short8*>(qp + 32);
  }
  float lrun[2][4];
  f32x4 oacc[2][4];
#pragma unroll
  for (int mf = 0; mf < 2; ++mf)
#pragma unroll
    for (int j = 0; j < 4; ++j) lrun[mf][j] = 0.f;
#pragma unroll
  for (int mf = 0; mf < 2; ++mf)
#pragma unroll
    for (int di = 0; di < 4; ++di) oacc[mf][di] = zero4();

  // prologue: K for the first iteration (only load that stays exposed)
  short8 kC[4][2];
  if (kt_begin < kt_end) {
    const int k0p = kt_begin * 64;
#pragma unroll
    for (int ni = 0; ni < 4; ++ni) {
      const __hip_bfloat16* kp =
          qkv + ((rb + k0p + ni * 16 + llo) * 3072 + h * 192 + 64 + lhi * 8);
      kC[ni][0] = *reinterpret_cast<const short8*>(kp);
      kC[ni][1] = *reinterpret_cast<const short8*>(kp + 32);
    }
  }

  for (int kt = kt_begin; kt < kt_end; ++kt) {
    const bool diag = (kt == nkv - 1);
    const bool evendiag = diag && (base == 0);  // ni>=2 / k>=32 dead
    const int k0 = kt * 64;
    short8 vC[4][2];
    // per-mf: QK -> mask -> exp2/store (no max tracking; softmax shift-inv.)
#pragma unroll
    for (int mf = 0; mf < 2; ++mf) {
      f32x4 sc[4];
      __builtin_amdgcn_s_setprio(1);
#pragma unroll
      for (int ni = 0; ni < 4; ++ni) {
        sc[ni] = zero4();
        if (!evendiag || ni < 2) {
          sc[ni] = __builtin_amdgcn_mfma_f32_16x16x32_bf16(qf[mf][0], kC[ni][0], sc[ni], 0, 0, 0);
          sc[ni] = __builtin_amdgcn_mfma_f32_16x16x32_bf16(qf[mf][1], kC[ni][1], sc[ni], 0, 0, 0);
        }
      }
      __builtin_amdgcn_s_setprio(0);
      if (mf == 1) {
        // kC fully consumed by both QK phases: overwrite with NEXT iter's K.
        if (kt + 1 < kt_end) {
          const int k0n = (kt + 1) * 64;
#pragma unroll
          for (int ni = 0; ni < 4; ++ni) {
            const __hip_bfloat16* kp =
                qkv + ((rb + k0n + ni * 16 + llo) * 3072 + h * 192 + 64 + lhi * 8);
            kC[ni][0] = *reinterpret_cast<const short8*>(kp);
            kC[ni][1] = *reinterpret_cast<const short8*>(kp + 32);
          }
        }
        // V loads: latency hides under mf=1 exp phase
#pragma unroll
        for (int di = 0; di < 4; ++di) {
          const __hip_bfloat16* vp =
              vt + (vbase + (size_t)(di * 16 + llo) * T_DIM + k0 + lhi * 8);
          vC[di][0] = *reinterpret_cast<const short8*>(vp);
          vC[di][1] = *reinterpret_cast<const short8*>(vp + 32);
        }
      }
#pragma unroll
      for (int j = 0; j < 4; ++j) {
        const int ql = mf * 16 + lhi * 4 + j;
#pragma unroll
        for (int ni = 0; ni < 4; ++ni) {
          float sval = sc[ni][j];
          if (diag) sval = (ni * 16 + llo <= base + ql) ? sval : -1e30f;
          sP[s4][mf * 16 + lhi * 4 + j][ni * 16 + llo] = __float2bfloat16(exp2f(sval));
        }
      }
    }
    asm volatile("s_waitcnt lgkmcnt(0)" ::: "memory");  // P writes -> P reads
    // O += P V ; l += P 1
    __builtin_amdgcn_s_setprio(1);
#pragma unroll
    for (int mf = 0; mf < 2; ++mf) {
      const short8 pf0 = *reinterpret_cast<const short8*>(&sP[s4][mf * 16 + llo][lhi * 8]);
      const short8 pf1 = *reinterpret_cast<const short8*>(&sP[s4][mf * 16 + llo][32 + lhi * 8]);
      f32x4 lacc = zero4();
      lacc = __builtin_amdgcn_mfma_f32_16x16x32_bf16(pf0, onesb, lacc, 0, 0, 0);
      if (!evendiag)
        lacc = __builtin_amdgcn_mfma_f32_16x16x32_bf16(pf1, onesb, lacc, 0, 0, 0);
#pragma unroll
      for (int di = 0; di < 4; ++di) {
        oacc[mf][di] =
            __builtin_amdgcn_mfma_f32_16x16x32_bf16(pf0, vC[di][0], oacc[mf][di], 0, 0, 0);
        if (!evendiag)
          oacc[mf][di] =
              __builtin_amdgcn_mfma_f32_16x16x32_bf16(pf1, vC[di][1], oacc[mf][di], 0, 0, 0);
      }
#pragma unroll
      for (int j = 0; j < 4; ++j)
        lrun[mf][j] += lacc[j];
    }
    __builtin_amdgcn_s_setprio(0);
  }

  // ---- 4-way merge: plain sums (no max bookkeeping). s=0..2 stage partials,
  // s=3 combines. Stride 21 floats/lane: odd -> conflict-free across 32 banks.
#pragma unroll
  for (int mf = 0; mf < 2; ++mf) {
    __syncthreads();  // sP reads done / prior phase consumed
    if (s4 < 3) {
      float* dst = mrgf + (s4 * 64 + l) * 21;
#pragma unroll
      for (int di = 0; di < 4; ++di)
#pragma unroll
        for (int j = 0; j < 4; ++j) dst[di * 4 + j] = oacc[mf][di][j];
#pragma unroll
      for (int j = 0; j < 4; ++j) dst[16 + j] = lrun[mf][j];
    }
    __syncthreads();
    if (s4 == 3) {
#pragma unroll
      for (int j = 0; j < 4; ++j) {
        float lt = lrun[mf][j];
#pragma unroll
        for (int si = 0; si < 3; ++si) lt += mrgf[(si * 64 + l) * 21 + 16 + j];
        const float inv = 1.0f / lt;
        const size_t row = rb + q0 + mf * 16 + lhi * 4 + j;
#pragma unroll
        for (int di = 0; di < 4; ++di) {
          float o = oacc[mf][di][j];
#pragma unroll
          for (int si = 0; si < 3; ++si) o += mrgf[(si * 64 + l) * 21 + di * 4 + j];
          aout[row * 1024 + h * 64 + di * 16 + llo] = __float2bfloat16(o * inv);
        }
      }
    }
  }
}

// ---------------- launch ----------------
extern "C" void kernel_launch(void* const* d_in, const int* in_sizes, int n_in,
                              void* d_out, int out_size, void* d_ws, size_t ws_size,
                              hipStream_t stream) {
  (void)in_sizes; (void)n_in; (void)out_size; (void)ws_size;
  const float* x      = (const float*)d_in[0];
  const float* ln1_g  = (const float*)d_in[1];
  const float* ln1_b  = (const float*)d_in[2];
  const float* w_qkv  = (const float*)d_in[3];
  const float* b_qkv  = (const float*)d_in[4];
  const float* w_out  = (const float*)d_in[5];
  const float* b_out  = (const float*)d_in[6];
  const float* ln2_g  = (const float*)d_in[7];
  const float* ln2_b  = (const float*)d_in[8];
  const float* w_fc   = (const float*)d_in[9];
  const float* b_fc   = (const float*)d_in[10];
  const float* w_proj = (const float*)d_in[11];
  const float* b_proj = (const float*)d_in[12];
  float* out = (float*)d_out;

  const int M = 2 * T_DIM;  // 4096 rows
  char* wsp = (char*)d_ws;
  size_t off = 0;
  auto carve = [&](size_t bytes) {
    void* p = wsp + off;
    off += (bytes + 255) & ~(size_t)255;
    return p;
  };
  __hip_bfloat16* wt_qkv  = (__hip_bfloat16*)carve((size_t)3072 * 1024 * 2);
  __hip_bfloat16* wt_out  = (__hip_bfloat16*)carve((size_t)1024 * 1024 * 2);
  __hip_bfloat16* wt_fc   = (__hip_bfloat16*)carve((size_t)4096 * 1024 * 2);
  __hip_bfloat16* wt_proj = (__hip_bfloat16*)carve((size_t)1024 * 4096 * 2);
  __hip_bfloat16* ln1o    = (__hip_bfloat16*)carve((size_t)M * 1024 * 2);
  __hip_bfloat16* qkvb    = (__hip_bfloat16*)carve((size_t)M * 3072 * 2);
  __hip_bfloat16* vtb     = (__hip_bfloat16*)carve((size_t)2 * NH * 64 * T_DIM * 2);
  __hip_bfloat16* attnb   = (__hip_bfloat16*)carve((size_t)M * 1024 * 2);
  float*          x2      = (float*)carve((size_t)M * 1024 * 4);
  __hip_bfloat16* h1      = (__hip_bfloat16*)carve((size_t)M * 4096 * 2);
  __hip_bfloat16* ln2o    = ln1o;  // ln1 output dead after QKV GEMM; reuse

  // fused prologue: 4 weight transposes + LN1 in one launch
  prep<<<4096, 256, 0, stream>>>(w_qkv, w_out, w_fc, w_proj,
                                 wt_qkv, wt_out, wt_fc, wt_proj,
                                 x, ln1_g, ln1_b, ln1o);
  gemm_bt<0, 0, 0, 1><<<dim3(3072 / 128, M / 128), 256, 0, stream>>>(
      ln1o, wt_qkv, b_qkv, nullptr, nullptr, qkvb, vtb, M, 3072, 1024);
  attn_fwd<<<dim3(32, 64), 256, 0, stream>>>(qkvb, vtb, attnb);
  gemm_small<1, 1><<<dim3(1024 / 128, M / 64), 256, 0, stream>>>(
      attnb, wt_out, b_out, x, x2, nullptr, M, 1024, 1024);
  layernorm_bf16<<<M / 4, 256, 0, stream>>>(x2, ln2_g, ln2_b, ln2o);
  gemm_bt<1, 0, 0, 0><<<dim3(4096 / 128, M / 128), 256, 0, stream>>>(
      ln2o, wt_fc, b_fc, nullptr, nullptr, h1, nullptr, M, 4096, 1024);
  gemm_small<1, 1><<<dim3(1024 / 128, M / 64), 256, 0, stream>>>(
      h1, wt_proj, b_proj, x2, out, nullptr, M, 1024, 4096);
}

// Round 29
// 256.095 us; speedup vs baseline: 1.0560x; 1.0061x over previous
//
#include <hip/hip_runtime.h>
#include <hip/hip_bf16.h>

// Transformer block forward: B=2, T=2048, E=1024, H=16, D=64.
// Pipeline: prep (transposes+LN1) | QKV GEMM (128^2 swz, V transposed in
//           epilogue, Q pre-scaled by 0.125*log2e) | flash attn v15 (no-max
//           base-2 softmax + next-K prefetch) | out-proj+res -> bf16 x2 |
//           LN2 (bf16 in) | FC+GELU (128^2) | proj + bf16-res -> f32 out.

#define T_DIM 2048
#define E_DIM 1024
#define NH 16

using short8 = __attribute__((__ext_vector_type__(8))) short;
using f32x4  = __attribute__((__ext_vector_type__(4))) float;

static __device__ __forceinline__ f32x4 zero4() {
  f32x4 z = {0.f, 0.f, 0.f, 0.f};
  return z;
}

static __device__ __forceinline__ unsigned short f2bfbits(float f) {
  __hip_bfloat16 h = __float2bfloat16(f);
  return *reinterpret_cast<unsigned short*>(&h);
}

static __device__ __forceinline__ float bf2f(unsigned short u) {
  union { unsigned int i; float f; } cv;
  cv.i = ((unsigned int)u) << 16;
  return cv.f;
}

static __device__ __forceinline__ float gelu_tanh(float x) {
  float z = 0.7978845608028654f * (x + 0.044715f * x * x * x);
  float e = __expf(2.0f * z);
  float th = 1.0f - 2.0f / (e + 1.0f);
  return 0.5f * x * (1.0f + th);
}

// ---------------- prep: 4 weight transposes (f32 [K][N] -> bf16 [N][K]) + LN1 ----
__global__ __launch_bounds__(256) void prep(
    const float* __restrict__ w_qkv, const float* __restrict__ w_out,
    const float* __restrict__ w_fc, const float* __restrict__ w_proj,
    __hip_bfloat16* __restrict__ t_qkv, __hip_bfloat16* __restrict__ t_out,
    __hip_bfloat16* __restrict__ t_fc, __hip_bfloat16* __restrict__ t_proj,
    const float* __restrict__ x, const float* __restrict__ g,
    const float* __restrict__ bb, __hip_bfloat16* __restrict__ ln1o) {
  __shared__ float tl[64][65];
  const int id = blockIdx.x;
  const int t = threadIdx.x;
  if (id < 3072) {
    const float* in;
    __hip_bfloat16* out;
    int K, N, bx, by;
    if (id < 768) {
      in = w_qkv; out = t_qkv; K = 1024; N = 3072; bx = id % 48; by = id / 48;
    } else if (id < 1024) {
      const int i = id - 768;
      in = w_out; out = t_out; K = 1024; N = 1024; bx = i % 16; by = i / 16;
    } else if (id < 2048) {
      const int i = id - 1024;
      in = w_fc; out = t_fc; K = 1024; N = 4096; bx = i % 64; by = i / 64;
    } else {
      const int i = id - 2048;
      in = w_proj; out = t_proj; K = 4096; N = 1024; bx = i % 16; by = i / 16;
    }
    const int n0 = bx * 64, k0 = by * 64;
    const int rr = t >> 4;        // 0..15
    const int cc = (t & 15) * 4;  // 0..60
#pragma unroll
    for (int i = 0; i < 4; ++i) {
      const int row = rr + i * 16;
      const float4 v = *reinterpret_cast<const float4*>(&in[(size_t)(k0 + row) * N + n0 + cc]);
      tl[row][cc] = v.x; tl[row][cc + 1] = v.y; tl[row][cc + 2] = v.z; tl[row][cc + 3] = v.w;
    }
    __syncthreads();
#pragma unroll
    for (int i = 0; i < 4; ++i) {
      const int row = rr + i * 16;  // output row (n)
      ushort4 pk;
      pk.x = f2bfbits(tl[cc + 0][row]);
      pk.y = f2bfbits(tl[cc + 1][row]);
      pk.z = f2bfbits(tl[cc + 2][row]);
      pk.w = f2bfbits(tl[cc + 3][row]);
      *reinterpret_cast<ushort4*>(&out[(size_t)(n0 + row) * K + k0 + cc]) = pk;
    }
  } else {
    // LN1 (f32 in -> bf16 out)
    const int lane = t & 63;
    const int row = (id - 3072) * 4 + (t >> 6);
    const float* xr = x + (size_t)row * E_DIM;
    float4 v[4];
    float s = 0.f, s2 = 0.f;
#pragma unroll
    for (int i = 0; i < 4; ++i) {
      v[i] = *reinterpret_cast<const float4*>(&xr[(i * 64 + lane) * 4]);
      s  += v[i].x + v[i].y + v[i].z + v[i].w;
      s2 += v[i].x * v[i].x + v[i].y * v[i].y + v[i].z * v[i].z + v[i].w * v[i].w;
    }
#pragma unroll
    for (int m = 1; m < 64; m <<= 1) { s += __shfl_xor(s, m); s2 += __shfl_xor(s2, m); }
    const float mu = s * (1.0f / E_DIM);
    const float var = s2 * (1.0f / E_DIM) - mu * mu;
    const float rstd = rsqrtf(var + 1e-5f);
    __hip_bfloat16* orow = ln1o + (size_t)row * E_DIM;
#pragma unroll
    for (int i = 0; i < 4; ++i) {
      const int col = (i * 64 + lane) * 4;
      const float4 gv = *reinterpret_cast<const float4*>(&g[col]);
      const float4 bv = *reinterpret_cast<const float4*>(&bb[col]);
      ushort4 pk;
      pk.x = f2bfbits((v[i].x - mu) * rstd * gv.x + bv.x);
      pk.y = f2bfbits((v[i].y - mu) * rstd * gv.y + bv.y);
      pk.z = f2bfbits((v[i].z - mu) * rstd * gv.z + bv.z);
      pk.w = f2bfbits((v[i].w - mu) * rstd * gv.w + bv.w);
      *reinterpret_cast<ushort4*>(&orow[col]) = pk;
    }
  }
}

// ---------------- LayerNorm rows of 1024, bf16 in -> bf16 out (LN2) ----------
__global__ __launch_bounds__(256) void layernorm_b2b(
    const __hip_bfloat16* __restrict__ x, const float* __restrict__ g,
    const float* __restrict__ bb, __hip_bfloat16* __restrict__ out) {
  const int lane = threadIdx.x & 63;
  const int row = blockIdx.x * 4 + (threadIdx.x >> 6);
  const __hip_bfloat16* xr = x + (size_t)row * E_DIM;
  float v[16];
  float s = 0.f, s2 = 0.f;
#pragma unroll
  for (int i = 0; i < 2; ++i) {
    const short8 pk = *reinterpret_cast<const short8*>(&xr[(i * 64 + lane) * 8]);
#pragma unroll
    for (int k = 0; k < 8; ++k) {
      const float f = bf2f((unsigned short)pk[k]);
      v[i * 8 + k] = f;
      s += f;
      s2 += f * f;
    }
  }
#pragma unroll
  for (int m = 1; m < 64; m <<= 1) { s += __shfl_xor(s, m); s2 += __shfl_xor(s2, m); }
  const float mu = s * (1.0f / E_DIM);
  const float var = s2 * (1.0f / E_DIM) - mu * mu;
  const float rstd = rsqrtf(var + 1e-5f);
  __hip_bfloat16* orow = out + (size_t)row * E_DIM;
#pragma unroll
  for (int i = 0; i < 2; ++i) {
    const int col = (i * 64 + lane) * 8;
    const float4 g0 = *reinterpret_cast<const float4*>(&g[col]);
    const float4 g1 = *reinterpret_cast<const float4*>(&g[col + 4]);
    const float4 b0 = *reinterpret_cast<const float4*>(&bb[col]);
    const float4 b1 = *reinterpret_cast<const float4*>(&bb[col + 4]);
    short8 pk;
    pk[0] = (short)f2bfbits((v[i * 8 + 0] - mu) * rstd * g0.x + b0.x);
    pk[1] = (short)f2bfbits((v[i * 8 + 1] - mu) * rstd * g0.y + b0.y);
    pk[2] = (short)f2bfbits((v[i * 8 + 2] - mu) * rstd * g0.z + b0.z);
    pk[3] = (short)f2bfbits((v[i * 8 + 3] - mu) * rstd * g0.w + b0.w);
    pk[4] = (short)f2bfbits((v[i * 8 + 4] - mu) * rstd * g1.x + b1.x);
    pk[5] = (short)f2bfbits((v[i * 8 + 5] - mu) * rstd * g1.y + b1.y);
    pk[6] = (short)f2bfbits((v[i * 8 + 6] - mu) * rstd * g1.z + b1.z);
    pk[7] = (short)f2bfbits((v[i * 8 + 7] - mu) * rstd * g1.w + b1.w);
    *reinterpret_cast<short8*>(&orow[col]) = pk;
  }
}

// ---------------- 128^2 bf16 GEMM, T2-swizzled LDS, 3 waves/EU ----------------
// QKV_MODE: Q cols scaled by 0.125*log2e (base-2 softmax downstream); V cols
// written TRANSPOSED to vt[b][h][d][T]; K cols written normally to outB.
template <int GELU_ACT, int ADD_RES, int OUT_F32, int QKV_MODE>
__global__ __launch_bounds__(256, 3) void gemm_bt(
    const __hip_bfloat16* __restrict__ A, const __hip_bfloat16* __restrict__ Bt,
    const float* __restrict__ bias, const float* __restrict__ res,
    float* __restrict__ outF, __hip_bfloat16* __restrict__ outB,
    __hip_bfloat16* __restrict__ vt,
    int M, int N, int K) {
  __shared__ __hip_bfloat16 sA[2][128 * 32];
  __shared__ __hip_bfloat16 sB[2][128 * 32];
  const int tid = threadIdx.x;
  const int w = tid >> 6, l = tid & 63;
  const int lhi = l >> 4, llo = l & 15;
  const int gx = gridDim.x;
  int wg = blockIdx.y * gx + blockIdx.x;
  const int cpx = (gx * gridDim.y) >> 3;
  wg = (wg & 7) * cpx + (wg >> 3);
  const int m0 = (wg / gx) * 128, n0 = (wg % gx) * 128;
  const int wr = (w >> 1) * 64, wc = (w & 1) * 64;
  f32x4 acc[4][4];
#pragma unroll
  for (int i = 0; i < 4; ++i)
#pragma unroll
    for (int j = 0; j < 4; ++j) acc[i][j] = zero4();

  const int nt = K >> 5;
  const int cswz = (((tid & 3) ^ ((tid >> 2) & 3)) << 3);
  auto stage = [&](int buf, int t) {
    const int k0 = t << 5;
#pragma unroll
    for (int i = 0; i < 2; ++i) {
      const int r = i * 64 + (tid >> 2);
      const int e = i * 2048 + tid * 8;
      __builtin_amdgcn_global_load_lds(
          (const __attribute__((address_space(1))) void*)(A + (size_t)(m0 + r) * K + k0 + cswz),
          (__attribute__((address_space(3))) void*)(&sA[buf][e]), 16, 0, 0);
      __builtin_amdgcn_global_load_lds(
          (const __attribute__((address_space(1))) void*)(Bt + (size_t)(n0 + r) * K + k0 + cswz),
          (__attribute__((address_space(3))) void*)(&sB[buf][e]), 16, 0, 0);
    }
  };

  stage(0, 0);
  for (int t = 0; t < nt; ++t) {
    const int cur = t & 1;
    __syncthreads();
    if (t + 1 < nt) stage(cur ^ 1, t + 1);
    const __hip_bfloat16* pa = sA[cur];
    const __hip_bfloat16* pb = sB[cur];
    short8 af[4], bfr[4];
    const int gsw = (lhi ^ (llo & 3)) << 3;
#pragma unroll
    for (int i = 0; i < 4; ++i) {
      af[i]  = *reinterpret_cast<const short8*>(pa + (wr + i * 16 + llo) * 32 + gsw);
      bfr[i] = *reinterpret_cast<const short8*>(pb + (wc + i * 16 + llo) * 32 + gsw);
    }
#pragma unroll
    for (int mi = 0; mi < 4; ++mi)
#pragma unroll
      for (int ni = 0; ni < 4; ++ni)
        acc[mi][ni] = __builtin_amdgcn_mfma_f32_16x16x32_bf16(af[mi], bfr[ni], acc[mi][ni], 0, 0, 0);
  }

#pragma unroll
  for (int mi = 0; mi < 4; ++mi) {
#pragma unroll
    for (int ni = 0; ni < 4; ++ni) {
      const int row = m0 + wr + mi * 16 + lhi * 4;
      const int col = n0 + wc + ni * 16 + llo;
      const float bc = bias[col];
      if (QKV_MODE) {
        const int r192 = col % 192;
        if (r192 >= 128) {
          // V column: write transposed to vt[b][h][d][T] (4 consecutive t = 8B)
          const int hh = col / 192, d = r192 - 128;
          const int bb2 = row >> 11, tr = row & 2047;
          ushort4 pk;
          pk.x = f2bfbits(acc[mi][ni][0] + bc);
          pk.y = f2bfbits(acc[mi][ni][1] + bc);
          pk.z = f2bfbits(acc[mi][ni][2] + bc);
          pk.w = f2bfbits(acc[mi][ni][3] + bc);
          *reinterpret_cast<ushort4*>(
              &vt[((size_t)(bb2 * NH + hh) * 64 + d) * T_DIM + tr]) = pk;
          continue;
        }
        const float qs = (r192 < 64) ? 0.18033688f : 1.0f;  // 0.125*log2(e) for Q
#pragma unroll
        for (int j = 0; j < 4; ++j)
          outB[(size_t)(row + j) * N + col] = __float2bfloat16((acc[mi][ni][j] + bc) * qs);
      } else {
#pragma unroll
        for (int j = 0; j < 4; ++j) {
          float v = acc[mi][ni][j] + bc;
          if (GELU_ACT) v = gelu_tanh(v);
          if (ADD_RES) v += res[(size_t)(row + j) * N + col];
          if (OUT_F32) outF[(size_t)(row + j) * N + col] = v;
          else outB[(size_t)(row + j) * N + col] = __float2bfloat16(v);
        }
      }
    }
  }
}

// ---------------- 64x128 bf16 GEMM for N=1024 outputs ----------------
// RES_BF16: residual stream read as bf16 (halves x2 HBM traffic).
template <int ADD_RES, int OUT_F32, int RES_BF16>
__global__ __launch_bounds__(256, 3) void gemm_small(
    const __hip_bfloat16* __restrict__ A, const __hip_bfloat16* __restrict__ Bt,
    const float* __restrict__ bias, const void* __restrict__ res,
    float* __restrict__ outF, __hip_bfloat16* __restrict__ outB,
    int M, int N, int K) {
  __shared__ __hip_bfloat16 sA[2][64 * 32];
  __shared__ __hip_bfloat16 sB[2][128 * 32];
  const int tid = threadIdx.x;
  const int w = tid >> 6, l = tid & 63;
  const int lhi = l >> 4, llo = l & 15;
  const int gx = gridDim.x;
  int wg = blockIdx.y * gx + blockIdx.x;
  const int cpx = (gx * gridDim.y) >> 3;
  wg = (wg & 7) * cpx + (wg >> 3);
  const int m0 = (wg / gx) * 64, n0 = (wg % gx) * 128;
  const int wr = (w >> 1) * 32, wc = (w & 1) * 64;
  f32x4 acc[2][4];
#pragma unroll
  for (int i = 0; i < 2; ++i)
#pragma unroll
    for (int j = 0; j < 4; ++j) acc[i][j] = zero4();

  const int nt = K >> 5;
  const int cswz = (((tid & 3) ^ ((tid >> 2) & 3)) << 3);
  auto stage = [&](int buf, int t) {
    const int k0 = t << 5;
    {
      const int r = tid >> 2;
      const int e = tid * 8;
      __builtin_amdgcn_global_load_lds(
          (const __attribute__((address_space(1))) void*)(A + (size_t)(m0 + r) * K + k0 + cswz),
          (__attribute__((address_space(3))) void*)(&sA[buf][e]), 16, 0, 0);
    }
#pragma unroll
    for (int i = 0; i < 2; ++i) {
      const int r = i * 64 + (tid >> 2);
      const int e = i * 2048 + tid * 8;
      __builtin_amdgcn_global_load_lds(
          (const __attribute__((address_space(1))) void*)(Bt + (size_t)(n0 + r) * K + k0 + cswz),
          (__attribute__((address_space(3))) void*)(&sB[buf][e]), 16, 0, 0);
    }
  };

  stage(0, 0);
  for (int t = 0; t < nt; ++t) {
    const int cur = t & 1;
    __syncthreads();
    if (t + 1 < nt) stage(cur ^ 1, t + 1);
    const __hip_bfloat16* pa = sA[cur];
    const __hip_bfloat16* pb = sB[cur];
    short8 af[2], bfr[4];
    const int gsw = (lhi ^ (llo & 3)) << 3;
#pragma unroll
    for (int i = 0; i < 2; ++i)
      af[i] = *reinterpret_cast<const short8*>(pa + (wr + i * 16 + llo) * 32 + gsw);
#pragma unroll
    for (int i = 0; i < 4; ++i)
      bfr[i] = *reinterpret_cast<const short8*>(pb + (wc + i * 16 + llo) * 32 + gsw);
#pragma unroll
    for (int mi = 0; mi < 2; ++mi)
#pragma unroll
      for (int ni = 0; ni < 4; ++ni)
        acc[mi][ni] = __builtin_amdgcn_mfma_f32_16x16x32_bf16(af[mi], bfr[ni], acc[mi][ni], 0, 0, 0);
  }

#pragma unroll
  for (int mi = 0; mi < 2; ++mi) {
#pragma unroll
    for (int ni = 0; ni < 4; ++ni) {
      const int row = m0 + wr + mi * 16 + lhi * 4;
      const int col = n0 + wc + ni * 16 + llo;
      const float bc = bias[col];
#pragma unroll
      for (int j = 0; j < 4; ++j) {
        float v = acc[mi][ni][j] + bc;
        if (ADD_RES) {
          const size_t ri = (size_t)(row + j) * N + col;
          if (RES_BF16)
            v += bf2f(*reinterpret_cast<const unsigned short*>(
                &((const __hip_bfloat16*)res)[ri]));
          else
            v += ((const float*)res)[ri];
        }
        if (OUT_F32) outF[(size_t)(row + j) * N + col] = v;
        else outB[(size_t)(row + j) * N + col] = __float2bfloat16(v);
      }
    }
  }
}

// ---------------- causal flash attention v15: no-max + next-K prefetch -------
// (round-26/28 verified best: ~75us, VGPR 84, no spill)
__global__ __launch_bounds__(256, 3) void attn_fwd(
    const __hip_bfloat16* __restrict__ qkv, const __hip_bfloat16* __restrict__ vt,
    __hip_bfloat16* __restrict__ aout) {
  const int hb = blockIdx.x;
  const int h = hb & 15, b = hb >> 4;
  const int tid = threadIdx.x, s4 = tid >> 6, l = tid & 63;
  const int lhi = l >> 4, llo = l & 15;
  const int tile = 63 - (int)blockIdx.y;  // heavy-first
  const size_t rb = (size_t)b * T_DIM;
  const size_t vbase = ((size_t)(b * NH + h) * 64) * T_DIM;
  __shared__ __align__(16) unsigned char smem[18432];  // sP 18432 >= merge 16128
  auto sP = reinterpret_cast<__hip_bfloat16(*)[32][72]>(smem);   // [4][32][72]
  float* mrgf = reinterpret_cast<float*>(smem);  // merge view: (s*64+l)*21 floats

  short8 onesb;
#pragma unroll
  for (int i = 0; i < 8; ++i) onesb[i] = (short)0x3F80;  // bf16 1.0

  const int q0 = tile * 32;
  const int nkv = (tile >> 1) + 1;       // kv-tiles of 64
  const int base = (tile & 1) << 5;      // diag offset: 0 or 32
  const int kt_begin = (s4 * nkv) >> 2;
  const int kt_end   = ((s4 + 1) * nkv) >> 2;

  short8 qf[2][2];
#pragma unroll
  for (int mf = 0; mf < 2; ++mf) {
    const __hip_bfloat16* qp =
        qkv + ((rb + q0 + mf * 16 + llo) * 3072 + h * 192 + lhi * 8);
    qf[mf][0] = *reinterpret_cast<const short8*>(qp);
    qf[mf][1] = *reinterpret_cast<const short8*>(qp + 32);
  }
  float lrun[2][4];
  f32x4 oacc[2][4];
#pragma unroll
  for (int mf = 0; mf < 2; ++mf)
#pragma unroll
    for (int j = 0; j < 4; ++j) lrun[mf][j] = 0.f;
#pragma unroll
  for (int mf = 0; mf < 2; ++mf)
#pragma unroll
    for (int di = 0; di < 4; ++di) oacc[mf][di] = zero4();

  // prologue: K for the first iteration (only load that stays exposed)
  short8 kC[4][2];
  if (kt_begin < kt_end) {
    const int k0p = kt_begin * 64;
#pragma unroll
    for (int ni = 0; ni < 4; ++ni) {
      const __hip_bfloat16* kp =
          qkv + ((rb + k0p + ni * 16 + llo) * 3072 + h * 192 + 64 + lhi * 8);
      kC[ni][0] = *reinterpret_cast<const short8*>(kp);
      kC[ni][1] = *reinterpret_cast<const short8*>(kp + 32);
    }
  }

  for (int kt = kt_begin; kt < kt_end; ++kt) {
    const bool diag = (kt == nkv - 1);
    const bool evendiag = diag && (base == 0);  // ni>=2 / k>=32 dead
    const int k0 = kt * 64;
    short8 vC[4][2];
    // per-mf: QK -> mask -> exp2/store (no max tracking; softmax shift-inv.)
#pragma unroll
    for (int mf = 0; mf < 2; ++mf) {
      f32x4 sc[4];
      __builtin_amdgcn_s_setprio(1);
#pragma unroll
      for (int ni = 0; ni < 4; ++ni) {
        sc[ni] = zero4();
        if (!evendiag || ni < 2) {
          sc[ni] = __builtin_amdgcn_mfma_f32_16x16x32_bf16(qf[mf][0], kC[ni][0], sc[ni], 0, 0, 0);
          sc[ni] = __builtin_amdgcn_mfma_f32_16x16x32_bf16(qf[mf][1], kC[ni][1], sc[ni], 0, 0, 0);
        }
      }
      __builtin_amdgcn_s_setprio(0);
      if (mf == 1) {
        // kC fully consumed by both QK phases: overwrite with NEXT iter's K.
        if (kt + 1 < kt_end) {
          const int k0n = (kt + 1) * 64;
#pragma unroll
          for (int ni = 0; ni < 4; ++ni) {
            const __hip_bfloat16* kp =
                qkv + ((rb + k0n + ni * 16 + llo) * 3072 + h * 192 + 64 + lhi * 8);
            kC[ni][0] = *reinterpret_cast<const short8*>(kp);
            kC[ni][1] = *reinterpret_cast<const short8*>(kp + 32);
          }
        }
        // V loads: latency hides under mf=1 exp phase
#pragma unroll
        for (int di = 0; di < 4; ++di) {
          const __hip_bfloat16* vp =
              vt + (vbase + (size_t)(di * 16 + llo) * T_DIM + k0 + lhi * 8);
          vC[di][0] = *reinterpret_cast<const short8*>(vp);
          vC[di][1] = *reinterpret_cast<const short8*>(vp + 32);
        }
      }
#pragma unroll
      for (int j = 0; j < 4; ++j) {
        const int ql = mf * 16 + lhi * 4 + j;
#pragma unroll
        for (int ni = 0; ni < 4; ++ni) {
          float sval = sc[ni][j];
          if (diag) sval = (ni * 16 + llo <= base + ql) ? sval : -1e30f;
          sP[s4][mf * 16 + lhi * 4 + j][ni * 16 + llo] = __float2bfloat16(exp2f(sval));
        }
      }
    }
    asm volatile("s_waitcnt lgkmcnt(0)" ::: "memory");  // P writes -> P reads
    // O += P V ; l += P 1
    __builtin_amdgcn_s_setprio(1);
#pragma unroll
    for (int mf = 0; mf < 2; ++mf) {
      const short8 pf0 = *reinterpret_cast<const short8*>(&sP[s4][mf * 16 + llo][lhi * 8]);
      const short8 pf1 = *reinterpret_cast<const short8*>(&sP[s4][mf * 16 + llo][32 + lhi * 8]);
      f32x4 lacc = zero4();
      lacc = __builtin_amdgcn_mfma_f32_16x16x32_bf16(pf0, onesb, lacc, 0, 0, 0);
      if (!evendiag)
        lacc = __builtin_amdgcn_mfma_f32_16x16x32_bf16(pf1, onesb, lacc, 0, 0, 0);
#pragma unroll
      for (int di = 0; di < 4; ++di) {
        oacc[mf][di] =
            __builtin_amdgcn_mfma_f32_16x16x32_bf16(pf0, vC[di][0], oacc[mf][di], 0, 0, 0);
        if (!evendiag)
          oacc[mf][di] =
              __builtin_amdgcn_mfma_f32_16x16x32_bf16(pf1, vC[di][1], oacc[mf][di], 0, 0, 0);
      }
#pragma unroll
      for (int j = 0; j < 4; ++j)
        lrun[mf][j] += lacc[j];
    }
    __builtin_amdgcn_s_setprio(0);
  }

  // ---- 4-way merge: plain sums (no max bookkeeping). s=0..2 stage partials,
  // s=3 combines. Stride 21 floats/lane: odd -> conflict-free across 32 banks.
#pragma unroll
  for (int mf = 0; mf < 2; ++mf) {
    __syncthreads();  // sP reads done / prior phase consumed
    if (s4 < 3) {
      float* dst = mrgf + (s4 * 64 + l) * 21;
#pragma unroll
      for (int di = 0; di < 4; ++di)
#pragma unroll
        for (int j = 0; j < 4; ++j) dst[di * 4 + j] = oacc[mf][di][j];
#pragma unroll
      for (int j = 0; j < 4; ++j) dst[16 + j] = lrun[mf][j];
    }
    __syncthreads();
    if (s4 == 3) {
#pragma unroll
      for (int j = 0; j < 4; ++j) {
        float lt = lrun[mf][j];
#pragma unroll
        for (int si = 0; si < 3; ++si) lt += mrgf[(si * 64 + l) * 21 + 16 + j];
        const float inv = 1.0f / lt;
        const size_t row = rb + q0 + mf * 16 + lhi * 4 + j;
#pragma unroll
        for (int di = 0; di < 4; ++di) {
          float o = oacc[mf][di][j];
#pragma unroll
          for (int si = 0; si < 3; ++si) o += mrgf[(si * 64 + l) * 21 + di * 4 + j];
          aout[row * 1024 + h * 64 + di * 16 + llo] = __float2bfloat16(o * inv);
        }
      }
    }
  }
}

// ---------------- launch ----------------
extern "C" void kernel_launch(void* const* d_in, const int* in_sizes, int n_in,
                              void* d_out, int out_size, void* d_ws, size_t ws_size,
                              hipStream_t stream) {
  (void)in_sizes; (void)n_in; (void)out_size; (void)ws_size;
  const float* x      = (const float*)d_in[0];
  const float* ln1_g  = (const float*)d_in[1];
  const float* ln1_b  = (const float*)d_in[2];
  const float* w_qkv  = (const float*)d_in[3];
  const float* b_qkv  = (const float*)d_in[4];
  const float* w_out  = (const float*)d_in[5];
  const float* b_out  = (const float*)d_in[6];
  const float* ln2_g  = (const float*)d_in[7];
  const float* ln2_b  = (const float*)d_in[8];
  const float* w_fc   = (const float*)d_in[9];
  const float* b_fc   = (const float*)d_in[10];
  const float* w_proj = (const float*)d_in[11];
  const float* b_proj = (const float*)d_in[12];
  float* out = (float*)d_out;

  const int M = 2 * T_DIM;  // 4096 rows
  char* wsp = (char*)d_ws;
  size_t off = 0;
  auto carve = [&](size_t bytes) {
    void* p = wsp + off;
    off += (bytes + 255) & ~(size_t)255;
    return p;
  };
  __hip_bfloat16* wt_qkv  = (__hip_bfloat16*)carve((size_t)3072 * 1024 * 2);
  __hip_bfloat16* wt_out  = (__hip_bfloat16*)carve((size_t)1024 * 1024 * 2);
  __hip_bfloat16* wt_fc   = (__hip_bfloat16*)carve((size_t)4096 * 1024 * 2);
  __hip_bfloat16* wt_proj = (__hip_bfloat16*)carve((size_t)1024 * 4096 * 2);
  __hip_bfloat16* ln1o    = (__hip_bfloat16*)carve((size_t)M * 1024 * 2);
  __hip_bfloat16* qkvb    = (__hip_bfloat16*)carve((size_t)M * 3072 * 2);
  __hip_bfloat16* vtb     = (__hip_bfloat16*)carve((size_t)2 * NH * 64 * T_DIM * 2);
  __hip_bfloat16* attnb   = (__hip_bfloat16*)carve((size_t)M * 1024 * 2);
  __hip_bfloat16* x2b     = (__hip_bfloat16*)carve((size_t)M * 1024 * 2);  // bf16 residual
  __hip_bfloat16* h1      = (__hip_bfloat16*)carve((size_t)M * 4096 * 2);
  __hip_bfloat16* ln2o    = ln1o;  // ln1 output dead after QKV GEMM; reuse

  // fused prologue: 4 weight transposes + LN1 in one launch
  prep<<<4096, 256, 0, stream>>>(w_qkv, w_out, w_fc, w_proj,
                                 wt_qkv, wt_out, wt_fc, wt_proj,
                                 x, ln1_g, ln1_b, ln1o);
  gemm_bt<0, 0, 0, 1><<<dim3(3072 / 128, M / 128), 256, 0, stream>>>(
      ln1o, wt_qkv, b_qkv, nullptr, nullptr, qkvb, vtb, M, 3072, 1024);
  attn_fwd<<<dim3(32, 64), 256, 0, stream>>>(qkvb, vtb, attnb);
  // out-proj + f32 residual(x) -> bf16 x2
  gemm_small<1, 0, 0><<<dim3(1024 / 128, M / 64), 256, 0, stream>>>(
      attnb, wt_out, b_out, (const void*)x, nullptr, x2b, M, 1024, 1024);
  layernorm_b2b<<<M / 4, 256, 0, stream>>>(x2b, ln2_g, ln2_b, ln2o);
  gemm_bt<1, 0, 0, 0><<<dim3(4096 / 128, M / 128), 256, 0, stream>>>(
      ln2o, wt_fc, b_fc, nullptr, nullptr, h1, nullptr, M, 4096, 1024);
  // proj + bf16 residual(x2) -> f32 out
  gemm_small<1, 1, 1><<<dim3(1024 / 128, M / 64), 256, 0, stream>>>(
      h1, wt_proj, b_proj, (const void*)x2b, out, nullptr, M, 1024, 4096);
}